// Round 10
// baseline (699.529 us; speedup 1.0000x reference)
//
#include <hip/hip_runtime.h>
#include <math.h>

typedef _Float16 h2 __attribute__((ext_vector_type(2)));
typedef _Float16 f16x8 __attribute__((ext_vector_type(8)));
typedef __attribute__((ext_vector_type(8))) short bf16x8;
typedef __attribute__((ext_vector_type(4))) float f32x4;

__device__ __forceinline__ float sigm(float x){ return 1.f/(1.f+expf(-x)); }

__device__ __forceinline__ float fsigm(float x){
  float e = __expf(-x);
  return __builtin_amdgcn_rcpf(1.f + e);
}
__device__ __forceinline__ float ftanh(float x){
  float xx = fminf(fmaxf(x, -15.f), 15.f);
  float e = __expf(2.f * xx);
  return 1.f - 2.f * __builtin_amdgcn_rcpf(e + 1.f);
}
__device__ __forceinline__ unsigned short f2bf(float f){
  union{float f; unsigned u;} x; x.f = f;
  unsigned r = x.u + 0x7FFF + ((x.u >> 16) & 1);
  return (unsigned short)(r >> 16);
}

// ---------------- K1: entity pooling + in-block ballot compaction ----------------
__global__ void k_ent_state(const float* __restrict__ doc, const float* __restrict__ emap,
                            float* __restrict__ ES, _Float16* __restrict__ ES16){
  int ne = blockIdx.x;            // 1024
  int n = ne >> 7;
  int tid = threadIdx.x;          // 256 = d
  __shared__ int idx_l[512];
  __shared__ int cnt_s;
  if (tid < 64){
    int total = 0;
    for (int base = 0; base < 512; base += 64){
      float m = emap[(size_t)ne*512 + base + tid];
      unsigned long long mask = __ballot(m != 0.f);
      int pos = __popcll(mask & ((1ull << tid) - 1ull));
      if (m != 0.f) idx_l[total + pos] = base + tid;
      total += __popcll(mask);
    }
    if (tid == 0) cnt_s = total;
  }
  __syncthreads();
  int cnt = cnt_s;
  const float* dbase = doc + (size_t)n*512*256 + tid;
  const float* mrow = emap + (size_t)ne*512;
  float sum = 0.f, mx = -3.402823e38f, msum = 0.f;
  for (int i = 0; i < cnt; i++){
    int l = idx_l[i];             // uniform broadcast
    float m = mrow[l];
    float v = m * dbase[(size_t)l*256];
    sum += v; mx = fmaxf(mx, v); msum += m;
  }
  if (cnt < 512) mx = fmaxf(mx, 0.f);
  float elen = (msum == 0.f) ? 1.f : msum;
  float mean = sum / elen;
  float* o = ES + (size_t)ne*512;
  o[tid] = mx;
  o[256 + tid] = mean;
  _Float16* o16 = ES16 + (size_t)ne*512;
  o16[tid] = (_Float16)mx;
  o16[256 + tid] = (_Float16)mean;
}

// ---------------- K1b: W_type -> f16 transpose [ht][f][k] ----------------
__global__ __launch_bounds__(256) void k_wtprep(const float* __restrict__ Wt,
                                                _Float16* __restrict__ WtT){
  int kt = blockIdx.x;            // 8 tiles of 64 k
  int ht = blockIdx.y;            // 12
  int tid = threadIdx.x;          // 256
  __shared__ _Float16 tile[64][65];
  for (int rep = 0; rep < 16; rep++){
    int linear = rep*256 + tid;
    int k = linear >> 6, f = linear & 63;
    tile[f][k] = (_Float16)Wt[((size_t)ht*512 + kt*64 + k)*64 + f];
  }
  __syncthreads();
  for (int rep = 0; rep < 16; rep++){
    int linear = rep*256 + tid;
    int f = linear >> 6, k = linear & 63;
    WtT[((size_t)ht*64 + f)*512 + kt*64 + k] = tile[f][k];
  }
}

// ---------------- K1c: Whh -> MFMA A-fragment pack, gate-interleaved ----------------
// GI row = j*4 + q (orig row q*128 + j). slot = ((w*4+mt)*4+kc)*64 + lane,
// lane = (khi<<4)|lane_lo; frag elem i: WhhGI[64w+16mt+lane_lo][32kc+8khi+i].
__global__ __launch_bounds__(256) void k_whhprep(const float* __restrict__ Whhf,
                                                 const float* __restrict__ Whhb,
                                                 _Float16* __restrict__ WA){
  int dir = blockIdx.y;
  const float* Whh = dir ? Whhb : Whhf;
  _Float16* outb = WA + (size_t)dir*512*128;
  int slot = blockIdx.x*256 + threadIdx.x;   // 8192 slots
  int l = slot & 63;
  int tile = slot >> 6;        // w*16 + mt*4 + kc
  int kc = tile & 3, mt = (tile >> 2) & 3, wv = tile >> 4;
  int lane_lo = l & 15, khi = l >> 4;
  int girow = wv*64 + mt*16 + lane_lo;
  int j = girow >> 2, q = girow & 3;
  const float* src = Whh + (size_t)(q*128 + j)*128 + kc*32 + khi*8;
  _Float16* dst = outb + (size_t)slot*8;
  #pragma unroll
  for (int i = 0; i < 8; i++) dst[i] = (_Float16)src[i];
}

// ---------------- K0b: compact nonzero-e lists per (n,l), tile-transposed ----------------
__global__ __launch_bounds__(256) void k_colidx(const float* __restrict__ emap,
                                                int* __restrict__ cidx, int* __restrict__ ccnt){
  int lt = blockIdx.x;            // 16 tiles of 32 l
  int n = blockIdx.y;             // 8
  int l0 = lt*32;
  int tid = threadIdx.x;          // 256
  __shared__ float tile[128][33];
  int l = tid & 31, eg = tid >> 5;
  for (int i = 0; i < 16; i++){
    int e = eg*16 + i;
    tile[e][l] = emap[((size_t)n*128 + e)*512 + l0 + l];
  }
  __syncthreads();
  if (tid < 32){
    int ll = tid;
    int b = n*512 + l0 + ll;
    int* outp = cidx + (size_t)b*128;
    int cnt = 0;
    for (int e = 0; e < 128; e++){
      if (tile[e][ll] != 0.f) outp[cnt++] = e;
    }
    ccnt[b] = cnt;
  }
}

// ---------------- K2: query = query_vec @ query_weight (64 blocks) ----------------
__global__ __launch_bounds__(256) void k_query2(const float* __restrict__ qv,
                                                const float* __restrict__ qw,
                                                float* __restrict__ Q){
  int b = blockIdx.x;             // 64 = n*8 + ct
  int n = b >> 3, ct = b & 7;
  int tid = threadIdx.x;
  int col = ct*64 + (tid & 63), ks = tid >> 6;
  const float* qvp = qv + n*512 + ks*128;
  const float* qwp = qw + (size_t)(ks*128)*512 + col;
  float acc = 0.f;
  for (int k = 0; k < 128; k++) acc += qvp[k] * qwp[(size_t)k*512];
  __shared__ float part[4][64];
  part[ks][tid & 63] = acc;
  __syncthreads();
  if (tid < 64)
    Q[n*512 + ct*64 + tid] = part[0][tid] + part[1][tid] + part[2][tid] + part[3][tid];
}

// ---------------- K3: query scores per (n,e), wave-reduced ----------------
__global__ __launch_bounds__(64) void k_qscore2(const float* __restrict__ ES,
                         const float* __restrict__ Q, const float* __restrict__ emask,
                         float* __restrict__ sm_out, float* __restrict__ AM){
  int ne = blockIdx.x;            // 1024
  int n = ne >> 7;
  int lane = threadIdx.x;
  const float* es = ES + (size_t)ne*512;
  const float* q = Q + n*512;
  float a = 0.f;
  for (int k = lane; k < 512; k += 64) a += es[k] * q[k];
  #pragma unroll
  for (int o = 32; o > 0; o >>= 1) a += __shfl_xor(a, o, 64);
  if (lane == 0){
    float s = (a * (1.f/512.f)) * emask[ne];
    sm_out[ne] = s;
    AM[ne] = sigm(s);
  }
}

// ---------------- K4: h_all = ES @ W_type via f16 MFMA ----------------
__global__ __launch_bounds__(256) void k_hall(const _Float16* __restrict__ ES16,
                                              const _Float16* __restrict__ WtT,
                                              float* __restrict__ HALL){
  int net = blockIdx.x;   // 16 tiles of 64 ne
  int ht  = blockIdx.y;   // 12
  int tid = threadIdx.x;
  int lane = tid & 63, w = tid >> 6;
  int wm = w >> 1, wg = w & 1;
  int m0 = net*64 + wm*32;
  int f0 = wg*32;
  int lr = lane & 15, lk8 = (lane >> 4) * 8;

  const _Float16* a0p = ES16 + (size_t)(m0 + lr)*512 + lk8;
  const _Float16* a1p = a0p + (size_t)16*512;
  const _Float16* b0p = WtT + ((size_t)ht*64 + f0 + lr)*512 + lk8;
  const _Float16* b1p = b0p + (size_t)16*512;

  f32x4 acc[2][2] = {};
  for (int k0 = 0; k0 < 512; k0 += 32){
    f16x8 af[2], bfr[2];
    af[0] = *(const f16x8*)a0p;
    af[1] = *(const f16x8*)a1p;
    bfr[0] = *(const f16x8*)b0p;
    bfr[1] = *(const f16x8*)b1p;
    a0p += 32; a1p += 32; b0p += 32; b1p += 32;
    #pragma unroll
    for (int im = 0; im < 2; im++)
      #pragma unroll
      for (int ig = 0; ig < 2; ig++)
        acc[im][ig] = __builtin_amdgcn_mfma_f32_16x16x32_f16(af[im], bfr[ig], acc[im][ig], 0, 0, 0);
  }
  int crow = (lane >> 4) * 4;
  int ccol = lane & 15;
  #pragma unroll
  for (int im = 0; im < 2; im++)
    #pragma unroll
    for (int ig = 0; ig < 2; ig++){
      int f = f0 + ig*16 + ccol;
      #pragma unroll
      for (int r = 0; r < 4; r++){
        int m = m0 + im*16 + crow + r;
        HALL[((size_t)ht*1024 + m)*64 + f] = acc[im][ig][r];
      }
    }
}

// ---------------- K5: qattn gates -> WSRC/WDST (96 blocks, k-split) ----------------
__global__ __launch_bounds__(256) void k_qattn(const float* __restrict__ qv,
                        const float* __restrict__ W1, const float* __restrict__ W2,
                        const float* __restrict__ at, float* __restrict__ WSRC,
                        float* __restrict__ WDST){
  int b = blockIdx.x;     // 96 = ht*8 + n
  int ht = b >> 3, n = b & 7;
  int tid = threadIdx.x;
  int f = tid & 127, kh = tid >> 7;
  __shared__ float qv_s[512];
  __shared__ float part[2][128];
  __shared__ float qg1[128];
  for (int i = tid; i < 512; i += 256) qv_s[i] = qv[n*512 + i];
  __syncthreads();
  const float* w1 = W1 + (size_t)ht*512*128 + (size_t)kh*256*128 + f;
  float acc = 0.f;
  for (int k = 0; k < 256; k++) acc += qv_s[kh*256 + k] * w1[(size_t)k*128];
  part[kh][f] = acc;
  __syncthreads();
  if (kh == 0) qg1[f] = fmaxf(part[0][f] + part[1][f], 0.f);
  __syncthreads();
  const float* w2 = W2 + (size_t)ht*128*128 + (size_t)kh*64*128 + f;
  float acc2 = 0.f;
  for (int g = 0; g < 64; g++) acc2 += qg1[kh*64 + g] * w2[(size_t)g*128];
  part[kh][f] = acc2;
  __syncthreads();
  if (kh == 0){
    float coef = sigm(part[0][f] + part[1][f]) * at[ht*128 + f];
    if (f < 64) WSRC[(ht*8 + n)*64 + f] = coef;
    else        WDST[(ht*8 + n)*64 + f - 64] = coef;
  }
}

// ---------------- K6: src/dst projections ----------------
__global__ void k_srcdst(const float* __restrict__ HALL, const float* __restrict__ WSRC,
                         const float* __restrict__ WDST, float* __restrict__ SRC,
                         float* __restrict__ DST){
  int b = blockIdx.x;     // ht*8+n, 96
  int e = threadIdx.x;    // 128
  __shared__ float w1[64], w2[64];
  if (e < 64) w1[e] = WSRC[b*64 + e]; else w2[e-64] = WDST[b*64 + e - 64];
  __syncthreads();
  int ht = b >> 3, n = b & 7;
  const float* h = HALL + ((size_t)ht*1024 + n*128 + e)*64;
  float s = 0.f, d = 0.f;
  #pragma unroll 8
  for (int f = 0; f < 64; f++){ float hv = h[f]; s += hv*w1[f]; d += hv*w2[f]; }
  SRC[b*128 + e] = s; DST[b*128 + e] = d;
}

// ---------------- K7: typed scores -> softmax -> heads -> entity_state2 ----------------
__global__ void k_attn(const float* __restrict__ HALL, const float* __restrict__ SRC,
                       const float* __restrict__ DST, const float* __restrict__ AM,
                       const int* __restrict__ adj, float* __restrict__ ES2,
                       float* __restrict__ out_ent){
  int b = blockIdx.x;                  // 256 = h(4) x n(8) x chunk(8)
  int h = b >> 6, n = (b >> 3) & 7, chunk = b & 7;
  int i0 = chunk*16;
  int tid = threadIdx.x;               // 128
  __shared__ float dst_l[3][128];
  __shared__ float src_l[3][16];
  __shared__ float hl[128][65];
  __shared__ float coef_l[128];
  __shared__ float redbuf[2];
  __shared__ float part2[2][64];
  for (int idx = tid; idx < 384; idx += 128){
    int t = idx >> 7, j = idx & 127;
    dst_l[t][j] = DST[((h*3 + t)*8 + n)*128 + j];
  }
  if (tid < 48){
    int t = tid >> 4, r = tid & 15;
    src_l[t][r] = SRC[((h*3 + t)*8 + n)*128 + i0 + r];
  }
  for (int idx = tid; idx < 8192; idx += 128){
    int j = idx >> 6, f = idx & 63;
    hl[j][f] = HALL[((size_t)(h*3 + 2)*1024 + n*128 + j)*64 + f] * AM[n*128 + j];
  }
  __syncthreads();
  const int* arow = adj + (size_t)n*128*128;
  int w = tid >> 6, f = tid & 63;
  for (int r = 0; r < 16; r++){
    int i = i0 + r;
    int a = arow[(size_t)i*128 + tid];
    float s;
    if (a > 0){
      float v = src_l[a-1][r] + dst_l[a-1][tid];
      s = v > 0.f ? v : 0.2f*v;
    } else s = -1e30f;
    float m = s;
    #pragma unroll
    for (int o = 32; o > 0; o >>= 1) m = fmaxf(m, __shfl_xor(m, o, 64));
    if ((tid & 63) == 0) redbuf[w] = m;
    __syncthreads();
    float mx = fmaxf(redbuf[0], redbuf[1]);
    float p = expf(s - mx);
    float ps = p;
    #pragma unroll
    for (int o = 32; o > 0; o >>= 1) ps += __shfl_xor(ps, o, 64);
    __syncthreads();
    if ((tid & 63) == 0) redbuf[w] = ps;
    __syncthreads();
    float denom = redbuf[0] + redbuf[1];
    coef_l[tid] = p / denom;
    __syncthreads();
    float acc = 0.f;
    for (int jj = 0; jj < 64; jj++) acc += coef_l[w*64 + jj] * hl[w*64 + jj][f];
    part2[w][f] = acc;
    __syncthreads();
    if (tid < 64){
      float v = fmaxf(part2[0][tid] + part2[1][tid], 0.f);
      size_t oidx = ((size_t)n*128 + i)*256 + h*64 + tid;
      ES2[oidx] = v;
      out_ent[oidx] = v;
    }
    __syncthreads();
  }
}

// ---------------- K8: expand entities back to tokens (sparse) ----------------
__global__ void k_expand(const float* __restrict__ ES2, const float* __restrict__ emap,
                         const float* __restrict__ doc, const int* __restrict__ cidx,
                         const int* __restrict__ ccnt, float* __restrict__ INP){
  int b = blockIdx.x;       // n*512+l, 4096
  int n = b >> 9, l = b & 511;
  int tid = threadIdx.x;    // 256
  int cnt = ccnt[b];
  const int* idx = cidx + (size_t)b*128;
  float acc = 0.f;
  const float* e2 = ES2 + (size_t)n*128*256 + tid;
  for (int i = 0; i < cnt; i++){
    int e = idx[i];
    float m = emap[((size_t)n*128 + e)*512 + l];
    acc += m * e2[(size_t)e*256];
  }
  float* o = INP + (size_t)b*512;
  o[tid] = acc;
  o[256 + tid] = doc[(size_t)b*256 + tid];
}

// ---------------- K9: input-projection GEMMs via bf16 MFMA ----------------
// Writes GATE-INTERLEAVED layout: G[m][j*4 + q], original g = q*128 + j.
__global__ __launch_bounds__(256) void k_gatein(const float* __restrict__ INP,
                         const float* __restrict__ Wf, const float* __restrict__ Wb,
                         const float* __restrict__ bihf, const float* __restrict__ bhhf,
                         const float* __restrict__ bihb, const float* __restrict__ bhhb,
                         float* __restrict__ GF, float* __restrict__ GB){
  int mt = blockIdx.x, gt = blockIdx.y, dir = blockIdx.z;
  const float* W = dir ? Wb : Wf;
  float* Gout = dir ? GB : GF;
  const float* bi = dir ? bihb : bihf;
  const float* bh = dir ? bhhb : bhhf;
  int tid = threadIdx.x;
  int lane = tid & 63, w = tid >> 6;
  int wm = w >> 1, wg = w & 1;
  int m0 = mt*64 + wm*32;
  int g0 = gt*64 + wg*32;
  int lr = lane & 15, lk8 = (lane >> 4) * 8;

  const float* a0p = INP + (size_t)(m0 + lr)*512 + lk8;
  const float* a1p = a0p + (size_t)16*512;
  const float* b0p = W   + (size_t)(g0 + lr)*512 + lk8;
  const float* b1p = b0p + (size_t)16*512;

  f32x4 acc[2][2] = {};
  for (int k0 = 0; k0 < 512; k0 += 32){
    bf16x8 af[2], bfr[2];
    {
      float4 u = *(const float4*)a0p, v = *(const float4*)(a0p + 4);
      bf16x8 r; r[0]=(short)f2bf(u.x); r[1]=(short)f2bf(u.y); r[2]=(short)f2bf(u.z); r[3]=(short)f2bf(u.w);
      r[4]=(short)f2bf(v.x); r[5]=(short)f2bf(v.y); r[6]=(short)f2bf(v.z); r[7]=(short)f2bf(v.w);
      af[0]=r;
    }
    {
      float4 u = *(const float4*)a1p, v = *(const float4*)(a1p + 4);
      bf16x8 r; r[0]=(short)f2bf(u.x); r[1]=(short)f2bf(u.y); r[2]=(short)f2bf(u.z); r[3]=(short)f2bf(u.w);
      r[4]=(short)f2bf(v.x); r[5]=(short)f2bf(v.y); r[6]=(short)f2bf(v.z); r[7]=(short)f2bf(v.w);
      af[1]=r;
    }
    {
      float4 u = *(const float4*)b0p, v = *(const float4*)(b0p + 4);
      bf16x8 r; r[0]=(short)f2bf(u.x); r[1]=(short)f2bf(u.y); r[2]=(short)f2bf(u.z); r[3]=(short)f2bf(u.w);
      r[4]=(short)f2bf(v.x); r[5]=(short)f2bf(v.y); r[6]=(short)f2bf(v.z); r[7]=(short)f2bf(v.w);
      bfr[0]=r;
    }
    {
      float4 u = *(const float4*)b1p, v = *(const float4*)(b1p + 4);
      bf16x8 r; r[0]=(short)f2bf(u.x); r[1]=(short)f2bf(u.y); r[2]=(short)f2bf(u.z); r[3]=(short)f2bf(u.w);
      r[4]=(short)f2bf(v.x); r[5]=(short)f2bf(v.y); r[6]=(short)f2bf(v.z); r[7]=(short)f2bf(v.w);
      bfr[1]=r;
    }
    a0p += 32; a1p += 32; b0p += 32; b1p += 32;
    #pragma unroll
    for (int im = 0; im < 2; im++)
      #pragma unroll
      for (int ig = 0; ig < 2; ig++)
        acc[im][ig] = __builtin_amdgcn_mfma_f32_16x16x32_bf16(af[im], bfr[ig], acc[im][ig], 0, 0, 0);
  }
  int crow = (lane >> 4) * 4;
  int ccol = lane & 15;
  #pragma unroll
  for (int im = 0; im < 2; im++)
    #pragma unroll
    for (int ig = 0; ig < 2; ig++){
      int g = g0 + ig*16 + ccol;
      float bias = bi[g] + bh[g];
      int p = (g & 127)*4 + (g >> 7);
      #pragma unroll
      for (int r = 0; r < 4; r++){
        int m = m0 + im*16 + crow + r;
        Gout[(size_t)m*512 + p] = acc[im][ig][r] + bias;
      }
    }
}

// ---------------- K10: MFMA-batched LSTM recurrence ----------------
// 2 blocks (dir) x 512 threads (8 waves). Per step: [512x128] WhhGI (A, in
// regs as prepped fragments) @ [128x8] h (B, LDS f16 [n][k] pad 136, dbuf)
// via 16x16x32 f16 MFMA. Wave w owns GI rows [64w,64w+64) (units 16w..+15,
// gate q=row&3). C layout: lane (col n = l&15, rows (l>>4)*4+q) -> each lane
// holds ALL 4 gates of unit j=16w+4mt+(l>>4) for seq n; no cross-lane
// exchange. G (gate-interleaved) = one float4 per (lane,mt). Cols 8-15 of B
// are zero rows; their lanes compute garbage but never write. Raw
// lgkmcnt-only barrier: G/out vmem stays in flight.
__global__ __launch_bounds__(512) void k_lstm(const float* __restrict__ GF,
                                              const float* __restrict__ GB,
                                              const _Float16* __restrict__ WA,
                                              float* __restrict__ out){
  int dir = blockIdx.x;
  const float* G = dir ? GB : GF;
  const _Float16* wa = WA + (size_t)dir*512*128;
  int tid = threadIdx.x;
  int lane = tid & 63, wv = tid >> 6;
  int n = lane & 15;
  int nc = n & 7;
  int uhi = lane >> 4;          // 0..3
  bool active = (n < 8);

  // A fragments: [mt][kc], each 8 f16
  f16x8 afrag[4][4];
  #pragma unroll
  for (int mt = 0; mt < 4; mt++)
    #pragma unroll
    for (int kc = 0; kc < 4; kc++){
      int slot = ((wv*4 + mt)*4 + kc)*64 + lane;
      afrag[mt][kc] = *(const f16x8*)(wa + (size_t)slot*8);
    }

  __shared__ __align__(16) _Float16 h_lds[2][16][136];
  for (int i = tid; i < 2*16*136; i += 512) ((_Float16*)h_lds)[i] = (_Float16)0.f;

  int j0 = 16*wv + uhi;         // + 4*mt per M-tile
  int tt0 = dir ? 511 : 0;
  const float* Gp = G + (size_t)(nc*512 + tt0)*512 + 4*j0;
  const long gstep = dir ? -512 : 512;
  float* outp = out + (size_t)(nc*512 + tt0)*256 + dir*128 + j0;
  const long ostep = dir ? -256 : 256;

  float4 gA[4], gB[4];
  #pragma unroll
  for (int mt = 0; mt < 4; mt++) gA[mt] = *(const float4*)(Gp + mt*16);
  Gp += gstep;
  #pragma unroll
  for (int mt = 0; mt < 4; mt++) gB[mt] = *(const float4*)(Gp + mt*16);
  Gp += gstep;

  float cst[4] = {0.f, 0.f, 0.f, 0.f};
  __syncthreads();

#define LSTM_STEP(RB, GREG)                                                    \
  {                                                                            \
    const _Float16* hrow = &h_lds[RB][n][0];                                   \
    f16x8 bfrag[4];                                                            \
    _Pragma("unroll")                                                          \
    for (int kc = 0; kc < 4; kc++)                                             \
      bfrag[kc] = *(const f16x8*)(hrow + kc*32 + uhi*8);                       \
    f32x4 acc[4] = {};                                                         \
    _Pragma("unroll")                                                          \
    for (int mt = 0; mt < 4; mt++)                                             \
      _Pragma("unroll")                                                        \
      for (int kc = 0; kc < 4; kc++)                                           \
        acc[mt] = __builtin_amdgcn_mfma_f32_16x16x32_f16(afrag[mt][kc],        \
                      bfrag[kc], acc[mt], 0, 0, 0);                            \
    _Pragma("unroll")                                                          \
    for (int mt = 0; mt < 4; mt++){                                            \
      float4 g = GREG[mt];                                                     \
      GREG[mt] = *(const float4*)(Gp + mt*16);                                 \
      float vi = acc[mt][0] + g.x, vf = acc[mt][1] + g.y;                      \
      float vg = acc[mt][2] + g.z, vo = acc[mt][3] + g.w;                      \
      cst[mt] = fsigm(vf)*cst[mt] + fsigm(vi)*ftanh(vg);                       \
      float hval = fsigm(vo)*ftanh(cst[mt]);                                   \
      if (active){                                                             \
        h_lds[RB^1][n][j0 + 4*mt] = (_Float16)hval;                            \
        outp[4*mt] = hval;                                                     \
      }                                                                        \
    }                                                                          \
    Gp += gstep;                                                               \
    outp += ostep;                                                             \
    asm volatile("s_waitcnt lgkmcnt(0)\n\ts_barrier" ::: "memory");            \
  }

  for (int t = 0; t < 512; t += 2){
    LSTM_STEP(0, gA)
    LSTM_STEP(1, gB)
  }
#undef LSTM_STEP
}

extern "C" void kernel_launch(void* const* d_in, const int* in_sizes, int n_in,
                              void* d_out, int out_size, void* d_ws, size_t ws_size,
                              hipStream_t stream){
  const float* doc   = (const float*)d_in[0];
  const float* qvec  = (const float*)d_in[1];
  const float* emap  = (const float*)d_in[3];
  const float* emask = (const float*)d_in[4];
  const float* qw    = (const float*)d_in[5];
  const float* Wt    = (const float*)d_in[6];
  const float* at    = (const float*)d_in[7];
  const float* qa1   = (const float*)d_in[8];
  const float* qa2   = (const float*)d_in[9];
  const float* Wihf  = (const float*)d_in[10];
  const float* Whhf  = (const float*)d_in[11];
  const float* bihf  = (const float*)d_in[12];
  const float* bhhf  = (const float*)d_in[13];
  const float* Wihb  = (const float*)d_in[14];
  const float* Whhb  = (const float*)d_in[15];
  const float* bihb  = (const float*)d_in[16];
  const float* bhhb  = (const float*)d_in[17];
  const int*   adj   = (const int*)d_in[19];

  float* out = (float*)d_out;
  float* out_doc = out;                         // 8*512*256
  float* out_ent = out + 8*512*256;             // 8*128*256
  float* out_sm  = out_ent + 8*128*256;         // 8*128

  float* w = (float*)d_ws;
  float* ES   = w; w += 8*128*512;
  float* AM   = w; w += 8*128;
  float* Q    = w; w += 8*512;
  float* HALL = w; w += 12*1024*64;
  float* WSRC = w; w += 12*8*64;
  float* WDST = w; w += 12*8*64;
  float* SRC  = w; w += 12*8*128;
  float* DST  = w; w += 12*8*128;
  float* ES2  = w; w += 8*128*256;
  float* INP  = w; w += 8*512*512;
  float* GF   = w; w += 8*512*512;
  w += 4096;                                    // prefetch overrun pad
  float* GB   = w; w += 8*512*512;
  w += 4096;                                    // safety pad
  _Float16* ES16 = (_Float16*)w; w += 8*128*512/2;
  _Float16* WtT  = (_Float16*)w; w += 12*64*512/2;
  _Float16* WA   = (_Float16*)w; w += 2*512*128/2;
  int* cidx = (int*)w; w += 4096*128;
  int* ccnt = (int*)w; w += 4096;

  hipLaunchKernelGGL(k_colidx,    dim3(16,8), dim3(256), 0, stream, emap, cidx, ccnt);
  hipLaunchKernelGGL(k_wtprep,    dim3(8,12), dim3(256), 0, stream, Wt, WtT);
  hipLaunchKernelGGL(k_whhprep,   dim3(32,2), dim3(256), 0, stream, Whhf, Whhb, WA);
  hipLaunchKernelGGL(k_ent_state, dim3(1024), dim3(256), 0, stream, doc, emap, ES, ES16);
  hipLaunchKernelGGL(k_query2,    dim3(64),   dim3(256), 0, stream, qvec, qw, Q);
  hipLaunchKernelGGL(k_qscore2,   dim3(1024), dim3(64),  0, stream, ES, Q, emask, out_sm, AM);
  hipLaunchKernelGGL(k_hall,      dim3(16,12),dim3(256), 0, stream, ES16, WtT, HALL);
  hipLaunchKernelGGL(k_qattn,     dim3(96),   dim3(256), 0, stream, qvec, qa1, qa2, at, WSRC, WDST);
  hipLaunchKernelGGL(k_srcdst,    dim3(96),   dim3(128), 0, stream, HALL, WSRC, WDST, SRC, DST);
  hipLaunchKernelGGL(k_attn,      dim3(256),  dim3(128), 0, stream, HALL, SRC, DST, AM, adj, ES2, out_ent);
  hipLaunchKernelGGL(k_expand,    dim3(4096), dim3(256), 0, stream, ES2, emap, doc, cidx, ccnt, INP);
  hipLaunchKernelGGL(k_gatein,    dim3(64,8,2), dim3(256), 0, stream, INP, Wihf, Wihb, bihf, bhhf, bihb, bhhb, GF, GB);
  hipLaunchKernelGGL(k_lstm,      dim3(2),    dim3(512), 0, stream, GF, GB, WA, out_doc);
}

// Round 11
// 394.330 us; speedup vs baseline: 1.7740x; 1.7740x over previous
//
#include <hip/hip_runtime.h>
#include <math.h>

typedef _Float16 h2 __attribute__((ext_vector_type(2)));
typedef _Float16 f16x8 __attribute__((ext_vector_type(8)));
typedef __attribute__((ext_vector_type(8))) short bf16x8;
typedef __attribute__((ext_vector_type(4))) float f32x4;

__device__ __forceinline__ float sigm(float x){ return 1.f/(1.f+expf(-x)); }

__device__ __forceinline__ float fsigm(float x){
  float e = __expf(-x);
  return __builtin_amdgcn_rcpf(1.f + e);
}
__device__ __forceinline__ float ftanh(float x){
  float xx = fminf(fmaxf(x, -15.f), 15.f);
  float e = __expf(2.f * xx);
  return 1.f - 2.f * __builtin_amdgcn_rcpf(e + 1.f);
}
__device__ __forceinline__ h2 u2h(unsigned u){
  union { unsigned u; h2 h; } x; x.u = u; return x.h;
}
template<int CTRL>
__device__ __forceinline__ float qperm(float v){
  return __int_as_float(__builtin_amdgcn_mov_dpp(__float_as_int(v), CTRL, 0xf, 0xf, true));
}
__device__ __forceinline__ unsigned short f2bf(float f){
  union{float f; unsigned u;} x; x.f = f;
  unsigned r = x.u + 0x7FFF + ((x.u >> 16) & 1);
  return (unsigned short)(r >> 16);
}

// =============== MEGA-1: all input-only kernels in one launch ===============
// blocks [0,128)    : colidx   (lt = b&15, n = b>>4)
// blocks [128,224)  : wtprep   (kt = rb&7, ht = rb>>3)
// blocks [224,1248) : ent_state (ne = rb)
// blocks [1248,1312): query2   (rb = n*8+ct)
// blocks [1312,1408): qattn    (rb = ht*8+n)
__global__ __launch_bounds__(256) void k_mega1(
    const float* __restrict__ doc, const float* __restrict__ emap,
    const float* __restrict__ qv, const float* __restrict__ qw,
    const float* __restrict__ Wt, const float* __restrict__ W1,
    const float* __restrict__ W2, const float* __restrict__ at,
    int* __restrict__ cidx, int* __restrict__ ccnt,
    _Float16* __restrict__ WtT, float* __restrict__ ES,
    _Float16* __restrict__ ES16, float* __restrict__ Q,
    float* __restrict__ WSRC, float* __restrict__ WDST){
  __shared__ __align__(16) char smem[16896];
  int b = blockIdx.x;
  int tid = threadIdx.x;

  if (b < 128){
    // ---- colidx: compact nonzero-e lists per (n,l), tile-transposed ----
    float (*tile)[33] = (float(*)[33])smem;     // [128][33]
    int lt = b & 15, n = b >> 4;
    int l0 = lt*32;
    int l = tid & 31, eg = tid >> 5;
    for (int i = 0; i < 16; i++){
      int e = eg*16 + i;
      tile[e][l] = emap[((size_t)n*128 + e)*512 + l0 + l];
    }
    __syncthreads();
    if (tid < 32){
      int ll = tid;
      int bb = n*512 + l0 + ll;
      int* outp = cidx + (size_t)bb*128;
      int cnt = 0;
      for (int e = 0; e < 128; e++){
        if (tile[e][ll] != 0.f) outp[cnt++] = e;
      }
      ccnt[bb] = cnt;
    }
  } else if (b < 224){
    // ---- wtprep: W_type -> f16 transpose [ht][f][k] ----
    _Float16 (*tile)[65] = (_Float16(*)[65])smem;   // [64][65]
    int rb = b - 128;
    int kt = rb & 7, ht = rb >> 3;
    for (int rep = 0; rep < 16; rep++){
      int linear = rep*256 + tid;
      int k = linear >> 6, f = linear & 63;
      tile[f][k] = (_Float16)Wt[((size_t)ht*512 + kt*64 + k)*64 + f];
    }
    __syncthreads();
    for (int rep = 0; rep < 16; rep++){
      int linear = rep*256 + tid;
      int f = linear >> 6, k = linear & 63;
      WtT[((size_t)ht*64 + f)*512 + kt*64 + k] = tile[f][k];
    }
  } else if (b < 1248){
    // ---- ent_state: pooling + in-block ballot compaction ----
    int* idx_l = (int*)smem;                    // [512]
    int* cnt_p = (int*)(smem + 2048);
    int ne = b - 224;
    int n = ne >> 7;
    if (tid < 64){
      int total = 0;
      for (int base = 0; base < 512; base += 64){
        float m = emap[(size_t)ne*512 + base + tid];
        unsigned long long mask = __ballot(m != 0.f);
        int pos = __popcll(mask & ((1ull << tid) - 1ull));
        if (m != 0.f) idx_l[total + pos] = base + tid;
        total += __popcll(mask);
      }
      if (tid == 0) *cnt_p = total;
    }
    __syncthreads();
    int cnt = *cnt_p;
    const float* dbase = doc + (size_t)n*512*256 + tid;
    const float* mrow = emap + (size_t)ne*512;
    float sum = 0.f, mx = -3.402823e38f, msum = 0.f;
    for (int i = 0; i < cnt; i++){
      int l = idx_l[i];
      float m = mrow[l];
      float v = m * dbase[(size_t)l*256];
      sum += v; mx = fmaxf(mx, v); msum += m;
    }
    if (cnt < 512) mx = fmaxf(mx, 0.f);
    float elen = (msum == 0.f) ? 1.f : msum;
    float mean = sum / elen;
    float* o = ES + (size_t)ne*512;
    o[tid] = mx;
    o[256 + tid] = mean;
    _Float16* o16 = ES16 + (size_t)ne*512;
    o16[tid] = (_Float16)mx;
    o16[256 + tid] = (_Float16)mean;
  } else if (b < 1312){
    // ---- query2 ----
    float (*part)[64] = (float(*)[64])smem;     // [4][64]
    int rb = b - 1248;
    int n = rb >> 3, ct = rb & 7;
    int col = ct*64 + (tid & 63), ks = tid >> 6;
    const float* qvp = qv + n*512 + ks*128;
    const float* qwp = qw + (size_t)(ks*128)*512 + col;
    float acc = 0.f;
    for (int k = 0; k < 128; k++) acc += qvp[k] * qwp[(size_t)k*512];
    part[ks][tid & 63] = acc;
    __syncthreads();
    if (tid < 64)
      Q[n*512 + ct*64 + tid] = part[0][tid] + part[1][tid] + part[2][tid] + part[3][tid];
  } else {
    // ---- qattn: gates -> WSRC/WDST ----
    float* qv_s = (float*)smem;                 // [512]
    float* partb = qv_s + 512;                  // [2][128]
    float* qg1 = partb + 256;                   // [128]
    int rb = b - 1312;
    int ht = rb >> 3, n = rb & 7;
    int f = tid & 127, kh = tid >> 7;
    for (int i = tid; i < 512; i += 256) qv_s[i] = qv[n*512 + i];
    __syncthreads();
    const float* w1 = W1 + (size_t)ht*512*128 + (size_t)kh*256*128 + f;
    float acc = 0.f;
    for (int k = 0; k < 256; k++) acc += qv_s[kh*256 + k] * w1[(size_t)k*128];
    partb[kh*128 + f] = acc;
    __syncthreads();
    if (kh == 0) qg1[f] = fmaxf(partb[f] + partb[128 + f], 0.f);
    __syncthreads();
    const float* w2 = W2 + (size_t)ht*128*128 + (size_t)kh*64*128 + f;
    float acc2 = 0.f;
    for (int g = 0; g < 64; g++) acc2 += qg1[kh*64 + g] * w2[(size_t)g*128];
    partb[kh*128 + f] = acc2;
    __syncthreads();
    if (kh == 0){
      float coef = sigm(partb[f] + partb[128 + f]) * at[ht*128 + f];
      if (f < 64) WSRC[(ht*8 + n)*64 + f] = coef;
      else        WDST[(ht*8 + n)*64 + f - 64] = coef;
    }
  }
}

// =============== MEGA-2: qscore2 (4 waves/block) + hall ===============
// blocks [0,256)  : qscore2, ne = b*4 + wave
// blocks [256,448): hall, idx = b-256: net = idx&15, ht = idx>>4
__global__ __launch_bounds__(256) void k_mega2(
    const float* __restrict__ ES, const float* __restrict__ Q,
    const float* __restrict__ emask, const _Float16* __restrict__ ES16,
    const _Float16* __restrict__ WtT, float* __restrict__ sm_out,
    float* __restrict__ AM, float* __restrict__ HALL){
  int b = blockIdx.x;
  int tid = threadIdx.x;
  if (b < 256){
    int wv = tid >> 6, lane = tid & 63;
    int ne = b*4 + wv;
    int n = ne >> 7;
    const float* es = ES + (size_t)ne*512;
    const float* q = Q + n*512;
    float a = 0.f;
    for (int k = lane; k < 512; k += 64) a += es[k] * q[k];
    #pragma unroll
    for (int o = 32; o > 0; o >>= 1) a += __shfl_xor(a, o, 64);
    if (lane == 0){
      float s = (a * (1.f/512.f)) * emask[ne];
      sm_out[ne] = s;
      AM[ne] = sigm(s);
    }
  } else {
    int idx = b - 256;
    int net = idx & 15, ht = idx >> 4;
    int lane = tid & 63, w = tid >> 6;
    int wm = w >> 1, wg = w & 1;
    int m0 = net*64 + wm*32;
    int f0 = wg*32;
    int lr = lane & 15, lk8 = (lane >> 4) * 8;

    const _Float16* a0p = ES16 + (size_t)(m0 + lr)*512 + lk8;
    const _Float16* a1p = a0p + (size_t)16*512;
    const _Float16* b0p = WtT + ((size_t)ht*64 + f0 + lr)*512 + lk8;
    const _Float16* b1p = b0p + (size_t)16*512;

    f32x4 acc[2][2] = {};
    for (int k0 = 0; k0 < 512; k0 += 32){
      f16x8 af[2], bfr[2];
      af[0] = *(const f16x8*)a0p;
      af[1] = *(const f16x8*)a1p;
      bfr[0] = *(const f16x8*)b0p;
      bfr[1] = *(const f16x8*)b1p;
      a0p += 32; a1p += 32; b0p += 32; b1p += 32;
      #pragma unroll
      for (int im = 0; im < 2; im++)
        #pragma unroll
        for (int ig = 0; ig < 2; ig++)
          acc[im][ig] = __builtin_amdgcn_mfma_f32_16x16x32_f16(af[im], bfr[ig], acc[im][ig], 0, 0, 0);
    }
    int crow = (lane >> 4) * 4;
    int ccol = lane & 15;
    #pragma unroll
    for (int im = 0; im < 2; im++)
      #pragma unroll
      for (int ig = 0; ig < 2; ig++){
        int f = f0 + ig*16 + ccol;
        #pragma unroll
        for (int r = 0; r < 4; r++){
          int m = m0 + im*16 + crow + r;
          HALL[((size_t)ht*1024 + m)*64 + f] = acc[im][ig][r];
        }
      }
  }
}

// ---------------- K6: src/dst projections ----------------
__global__ void k_srcdst(const float* __restrict__ HALL, const float* __restrict__ WSRC,
                         const float* __restrict__ WDST, float* __restrict__ SRC,
                         float* __restrict__ DST){
  int b = blockIdx.x;     // ht*8+n, 96
  int e = threadIdx.x;    // 128
  __shared__ float w1[64], w2[64];
  if (e < 64) w1[e] = WSRC[b*64 + e]; else w2[e-64] = WDST[b*64 + e - 64];
  __syncthreads();
  int ht = b >> 3, n = b & 7;
  const float* h = HALL + ((size_t)ht*1024 + n*128 + e)*64;
  float s = 0.f, d = 0.f;
  #pragma unroll 8
  for (int f = 0; f < 64; f++){ float hv = h[f]; s += hv*w1[f]; d += hv*w2[f]; }
  SRC[b*128 + e] = s; DST[b*128 + e] = d;
}

// ---------------- K7: typed scores -> softmax -> heads -> entity_state2 ----------------
__global__ void k_attn(const float* __restrict__ HALL, const float* __restrict__ SRC,
                       const float* __restrict__ DST, const float* __restrict__ AM,
                       const int* __restrict__ adj, float* __restrict__ ES2,
                       float* __restrict__ out_ent){
  int b = blockIdx.x;                  // 256 = h(4) x n(8) x chunk(8)
  int h = b >> 6, n = (b >> 3) & 7, chunk = b & 7;
  int i0 = chunk*16;
  int tid = threadIdx.x;               // 128
  __shared__ float dst_l[3][128];
  __shared__ float src_l[3][16];
  __shared__ float hl[128][65];
  __shared__ float coef_l[128];
  __shared__ float redbuf[2];
  __shared__ float part2[2][64];
  for (int idx = tid; idx < 384; idx += 128){
    int t = idx >> 7, j = idx & 127;
    dst_l[t][j] = DST[((h*3 + t)*8 + n)*128 + j];
  }
  if (tid < 48){
    int t = tid >> 4, r = tid & 15;
    src_l[t][r] = SRC[((h*3 + t)*8 + n)*128 + i0 + r];
  }
  for (int idx = tid; idx < 8192; idx += 128){
    int j = idx >> 6, f = idx & 63;
    hl[j][f] = HALL[((size_t)(h*3 + 2)*1024 + n*128 + j)*64 + f] * AM[n*128 + j];
  }
  __syncthreads();
  const int* arow = adj + (size_t)n*128*128;
  int w = tid >> 6, f = tid & 63;
  for (int r = 0; r < 16; r++){
    int i = i0 + r;
    int a = arow[(size_t)i*128 + tid];
    float s;
    if (a > 0){
      float v = src_l[a-1][r] + dst_l[a-1][tid];
      s = v > 0.f ? v : 0.2f*v;
    } else s = -1e30f;
    float m = s;
    #pragma unroll
    for (int o = 32; o > 0; o >>= 1) m = fmaxf(m, __shfl_xor(m, o, 64));
    if ((tid & 63) == 0) redbuf[w] = m;
    __syncthreads();
    float mx = fmaxf(redbuf[0], redbuf[1]);
    float p = expf(s - mx);
    float ps = p;
    #pragma unroll
    for (int o = 32; o > 0; o >>= 1) ps += __shfl_xor(ps, o, 64);
    __syncthreads();
    if ((tid & 63) == 0) redbuf[w] = ps;
    __syncthreads();
    float denom = redbuf[0] + redbuf[1];
    coef_l[tid] = p / denom;
    __syncthreads();
    float acc = 0.f;
    for (int jj = 0; jj < 64; jj++) acc += coef_l[w*64 + jj] * hl[w*64 + jj][f];
    part2[w][f] = acc;
    __syncthreads();
    if (tid < 64){
      float v = fmaxf(part2[0][tid] + part2[1][tid], 0.f);
      size_t oidx = ((size_t)n*128 + i)*256 + h*64 + tid;
      ES2[oidx] = v;
      out_ent[oidx] = v;
    }
    __syncthreads();
  }
}

// ---------------- K8: expand entities back to tokens (sparse) ----------------
__global__ void k_expand(const float* __restrict__ ES2, const float* __restrict__ emap,
                         const float* __restrict__ doc, const int* __restrict__ cidx,
                         const int* __restrict__ ccnt, float* __restrict__ INP){
  int b = blockIdx.x;       // n*512+l, 4096
  int n = b >> 9, l = b & 511;
  int tid = threadIdx.x;    // 256
  int cnt = ccnt[b];
  const int* idx = cidx + (size_t)b*128;
  float acc = 0.f;
  const float* e2 = ES2 + (size_t)n*128*256 + tid;
  for (int i = 0; i < cnt; i++){
    int e = idx[i];
    float m = emap[((size_t)n*128 + e)*512 + l];
    acc += m * e2[(size_t)e*256];
  }
  float* o = INP + (size_t)b*512;
  o[tid] = acc;
  o[256 + tid] = doc[(size_t)b*256 + tid];
}

// ---------------- K9: input-projection GEMMs via bf16 MFMA ----------------
// Writes GATE-INTERLEAVED layout: G[m][j*4 + q], original g = q*128 + j.
__global__ __launch_bounds__(256) void k_gatein(const float* __restrict__ INP,
                         const float* __restrict__ Wf, const float* __restrict__ Wb,
                         const float* __restrict__ bihf, const float* __restrict__ bhhf,
                         const float* __restrict__ bihb, const float* __restrict__ bhhb,
                         float* __restrict__ GF, float* __restrict__ GB){
  int mt = blockIdx.x, gt = blockIdx.y, dir = blockIdx.z;
  const float* W = dir ? Wb : Wf;
  float* Gout = dir ? GB : GF;
  const float* bi = dir ? bihb : bihf;
  const float* bh = dir ? bhhb : bhhf;
  int tid = threadIdx.x;
  int lane = tid & 63, w = tid >> 6;
  int wm = w >> 1, wg = w & 1;
  int m0 = mt*64 + wm*32;
  int g0 = gt*64 + wg*32;
  int lr = lane & 15, lk8 = (lane >> 4) * 8;

  const float* a0p = INP + (size_t)(m0 + lr)*512 + lk8;
  const float* a1p = a0p + (size_t)16*512;
  const float* b0p = W   + (size_t)(g0 + lr)*512 + lk8;
  const float* b1p = b0p + (size_t)16*512;

  f32x4 acc[2][2] = {};
  for (int k0 = 0; k0 < 512; k0 += 32){
    bf16x8 af[2], bfr[2];
    {
      float4 u = *(const float4*)a0p, v = *(const float4*)(a0p + 4);
      bf16x8 r; r[0]=(short)f2bf(u.x); r[1]=(short)f2bf(u.y); r[2]=(short)f2bf(u.z); r[3]=(short)f2bf(u.w);
      r[4]=(short)f2bf(v.x); r[5]=(short)f2bf(v.y); r[6]=(short)f2bf(v.z); r[7]=(short)f2bf(v.w);
      af[0]=r;
    }
    {
      float4 u = *(const float4*)a1p, v = *(const float4*)(a1p + 4);
      bf16x8 r; r[0]=(short)f2bf(u.x); r[1]=(short)f2bf(u.y); r[2]=(short)f2bf(u.z); r[3]=(short)f2bf(u.w);
      r[4]=(short)f2bf(v.x); r[5]=(short)f2bf(v.y); r[6]=(short)f2bf(v.z); r[7]=(short)f2bf(v.w);
      af[1]=r;
    }
    {
      float4 u = *(const float4*)b0p, v = *(const float4*)(b0p + 4);
      bf16x8 r; r[0]=(short)f2bf(u.x); r[1]=(short)f2bf(u.y); r[2]=(short)f2bf(u.z); r[3]=(short)f2bf(u.w);
      r[4]=(short)f2bf(v.x); r[5]=(short)f2bf(v.y); r[6]=(short)f2bf(v.z); r[7]=(short)f2bf(v.w);
      bfr[0]=r;
    }
    {
      float4 u = *(const float4*)b1p, v = *(const float4*)(b1p + 4);
      bf16x8 r; r[0]=(short)f2bf(u.x); r[1]=(short)f2bf(u.y); r[2]=(short)f2bf(u.z); r[3]=(short)f2bf(u.w);
      r[4]=(short)f2bf(v.x); r[5]=(short)f2bf(v.y); r[6]=(short)f2bf(v.z); r[7]=(short)f2bf(v.w);
      bfr[1]=r;
    }
    a0p += 32; a1p += 32; b0p += 32; b1p += 32;
    #pragma unroll
    for (int im = 0; im < 2; im++)
      #pragma unroll
      for (int ig = 0; ig < 2; ig++)
        acc[im][ig] = __builtin_amdgcn_mfma_f32_16x16x32_bf16(af[im], bfr[ig], acc[im][ig], 0, 0, 0);
  }
  int crow = (lane >> 4) * 4;
  int ccol = lane & 15;
  #pragma unroll
  for (int im = 0; im < 2; im++)
    #pragma unroll
    for (int ig = 0; ig < 2; ig++){
      int g = g0 + ig*16 + ccol;
      float bias = bi[g] + bh[g];
      int p = (g & 127)*4 + (g >> 7);
      #pragma unroll
      for (int r = 0; r < 4; r++){
        int m = m0 + im*16 + crow + r;
        Gout[(size_t)m*512 + p] = acc[im][ig][r] + bias;
      }
    }
}

// ---------------- K10: LSTM recurrence (R7 version — measured best) ----------------
// 16 blocks (n x dir) x 256 threads. Raw lgkmcnt-only barrier keeps G
// prefetch (depth 4) in flight across steps; G gate-interleaved float4.
// R10 lesson: fewer blocks concentrates the G-stream onto too few CUs and
// hits the ~24 GB/s per-CU HBM ceiling — 16 blocks is the sweet spot.
__global__ __launch_bounds__(256) void k_lstm(const float* __restrict__ GF,
                                              const float* __restrict__ GB,
                                              const float* __restrict__ Whhf,
                                              const float* __restrict__ Whhb,
                                              float* __restrict__ out){
  int b = blockIdx.x;          // 16
  int dir = b >> 3, n = b & 7;
  const float* G = dir ? GB : GF;
  const float* Whh = dir ? Whhb : Whhf;
  int tid = threadIdx.x;       // 256
  int j = tid >> 1;            // unit 0..127
  int s = tid & 1;             // k-slice half

  h2 wreg[4][32];
  #pragma unroll
  for (int q = 0; q < 4; q++){
    const float* wp = Whh + (size_t)(q*128 + j)*128 + 64*s;
    #pragma unroll
    for (int kk = 0; kk < 32; kk++){
      h2 p; p[0] = (_Float16)wp[2*kk]; p[1] = (_Float16)wp[2*kk+1];
      wreg[q][kk] = p;
    }
  }

  __shared__ __align__(16) _Float16 h_l[2][128];
  if (tid < 128) h_l[0][tid] = (_Float16)0.f;

  const float4* Gp = (const float4*)(G + (size_t)n*512*512) + (dir ? (size_t)511*128 : 0) + j;
  const int gstep = dir ? -128 : 128;
  float* outp = out + (size_t)n*512*256 + (dir ? (size_t)511*256 : 0) + dir*128 + j;
  const int ostep = dir ? -256 : 256;

  float4 ga, gb, gc, gd;
  ga = *Gp; Gp += gstep;
  gb = *Gp; Gp += gstep;
  gc = *Gp; Gp += gstep;
  gd = *Gp; Gp += gstep;
  float c = 0.f;
  __syncthreads();

#define LSTM_STEP(RB, GREG)                                                    \
  {                                                                            \
    const uint4* hb = (const uint4*)(&h_l[RB][64*s]);                          \
    uint4 hv[8];                                                               \
    _Pragma("unroll")                                                          \
    for (int r = 0; r < 8; r++) hv[r] = hb[r];                                 \
    float gci = GREG.x, gcf = GREG.y, gcg = GREG.z, gco = GREG.w;              \
    GREG = *Gp; Gp += gstep;                                                   \
    float accf[4];                                                             \
    _Pragma("unroll")                                                          \
    for (int q = 0; q < 4; q++){                                               \
      h2 a0; a0[0]=(_Float16)0.f; a0[1]=(_Float16)0.f; h2 a1 = a0;             \
      _Pragma("unroll")                                                        \
      for (int r = 0; r < 8; r++){                                             \
        a0 += wreg[q][4*r+0] * u2h(hv[r].x);                                   \
        a1 += wreg[q][4*r+1] * u2h(hv[r].y);                                   \
        a0 += wreg[q][4*r+2] * u2h(hv[r].z);                                   \
        a1 += wreg[q][4*r+3] * u2h(hv[r].w);                                   \
      }                                                                        \
      h2 hs = a0 + a1;                                                         \
      accf[q] = (float)hs[0] + (float)hs[1];                                   \
    }                                                                          \
    _Pragma("unroll")                                                          \
    for (int q = 0; q < 4; q++){                                               \
      accf[q] += qperm<0xB1>(accf[q]);                                         \
    }                                                                          \
    float vi = accf[0] + gci, vf = accf[1] + gcf;                              \
    float vg = accf[2] + gcg, vo = accf[3] + gco;                              \
    c = fsigm(vf) * c + fsigm(vi) * ftanh(vg);                                 \
    float hval = fsigm(vo) * ftanh(c);                                         \
    if (s == 0) h_l[RB^1][j] = (_Float16)hval;                                 \
    else        *outp = hval;                                                  \
    outp += ostep;                                                             \
    asm volatile("s_waitcnt lgkmcnt(0)\n\ts_barrier" ::: "memory");            \
  }

  for (int t = 0; t < 512; t += 4){
    LSTM_STEP(0, ga)
    LSTM_STEP(1, gb)
    LSTM_STEP(0, gc)
    LSTM_STEP(1, gd)
  }
#undef LSTM_STEP
}

extern "C" void kernel_launch(void* const* d_in, const int* in_sizes, int n_in,
                              void* d_out, int out_size, void* d_ws, size_t ws_size,
                              hipStream_t stream){
  const float* doc   = (const float*)d_in[0];
  const float* qvec  = (const float*)d_in[1];
  const float* emap  = (const float*)d_in[3];
  const float* emask = (const float*)d_in[4];
  const float* qw    = (const float*)d_in[5];
  const float* Wt    = (const float*)d_in[6];
  const float* at    = (const float*)d_in[7];
  const float* qa1   = (const float*)d_in[8];
  const float* qa2   = (const float*)d_in[9];
  const float* Wihf  = (const float*)d_in[10];
  const float* Whhf  = (const float*)d_in[11];
  const float* bihf  = (const float*)d_in[12];
  const float* bhhf  = (const float*)d_in[13];
  const float* Wihb  = (const float*)d_in[14];
  const float* Whhb  = (const float*)d_in[15];
  const float* bihb  = (const float*)d_in[16];
  const float* bhhb  = (const float*)d_in[17];
  const int*   adj   = (const int*)d_in[19];

  float* out = (float*)d_out;
  float* out_doc = out;                         // 8*512*256
  float* out_ent = out + 8*512*256;             // 8*128*256
  float* out_sm  = out_ent + 8*128*256;         // 8*128

  float* w = (float*)d_ws;
  float* ES   = w; w += 8*128*512;
  float* AM   = w; w += 8*128;
  float* Q    = w; w += 8*512;
  float* HALL = w; w += 12*1024*64;
  float* WSRC = w; w += 12*8*64;
  float* WDST = w; w += 12*8*64;
  float* SRC  = w; w += 12*8*128;
  float* DST  = w; w += 12*8*128;
  float* ES2  = w; w += 8*128*256;
  float* INP  = w; w += 8*512*512;
  float* GF   = w; w += 8*512*512;
  w += 4096;                                    // prefetch overrun pad
  float* GB   = w; w += 8*512*512;
  w += 4096;                                    // safety pad
  _Float16* ES16 = (_Float16*)w; w += 8*128*512/2;
  _Float16* WtT  = (_Float16*)w; w += 12*64*512/2;
  int* cidx = (int*)w; w += 4096*128;
  int* ccnt = (int*)w; w += 4096;

  hipLaunchKernelGGL(k_mega1,  dim3(1408), dim3(256), 0, stream,
                     doc, emap, qvec, qw, Wt, qa1, qa2, at,
                     cidx, ccnt, WtT, ES, ES16, Q, WSRC, WDST);
  hipLaunchKernelGGL(k_mega2,  dim3(448),  dim3(256), 0, stream,
                     ES, Q, emask, ES16, WtT, out_sm, AM, HALL);
  hipLaunchKernelGGL(k_srcdst, dim3(96),   dim3(128), 0, stream, HALL, WSRC, WDST, SRC, DST);
  hipLaunchKernelGGL(k_attn,   dim3(256),  dim3(128), 0, stream, HALL, SRC, DST, AM, adj, ES2, out_ent);
  hipLaunchKernelGGL(k_expand, dim3(4096), dim3(256), 0, stream, ES2, emap, doc, cidx, ccnt, INP);
  hipLaunchKernelGGL(k_gatein, dim3(64,8,2), dim3(256), 0, stream, INP, Wihf, Wihb, bihf, bhhf, bihb, bhhb, GF, GB);
  hipLaunchKernelGGL(k_lstm,   dim3(16),   dim3(256), 0, stream, GF, GB, Whhf, Whhb, out_doc);
}

// Round 12
// 393.959 us; speedup vs baseline: 1.7756x; 1.0009x over previous
//
#include <hip/hip_runtime.h>
#include <math.h>

typedef _Float16 h2 __attribute__((ext_vector_type(2)));
typedef _Float16 f16x8 __attribute__((ext_vector_type(8)));
typedef __attribute__((ext_vector_type(8))) short bf16x8;
typedef __attribute__((ext_vector_type(4))) float f32x4;

__device__ __forceinline__ float sigm(float x){ return 1.f/(1.f+expf(-x)); }

__device__ __forceinline__ float fsigm(float x){
  float e = __expf(-x);
  return __builtin_amdgcn_rcpf(1.f + e);
}
__device__ __forceinline__ float ftanh(float x){
  float xx = fminf(fmaxf(x, -15.f), 15.f);
  float e = __expf(2.f * xx);
  return 1.f - 2.f * __builtin_amdgcn_rcpf(e + 1.f);
}
__device__ __forceinline__ h2 u2h(unsigned u){
  union { unsigned u; h2 h; } x; x.u = u; return x.h;
}
template<int CTRL>
__device__ __forceinline__ float qperm(float v){
  return __int_as_float(__builtin_amdgcn_mov_dpp(__float_as_int(v), CTRL, 0xf, 0xf, true));
}
__device__ __forceinline__ unsigned short f2bf(float f){
  union{float f; unsigned u;} x; x.f = f;
  unsigned r = x.u + 0x7FFF + ((x.u >> 16) & 1);
  return (unsigned short)(r >> 16);
}

// =============== MEGA-1: all input-only kernels in one launch ===============
__global__ __launch_bounds__(256) void k_mega1(
    const float* __restrict__ doc, const float* __restrict__ emap,
    const float* __restrict__ qv, const float* __restrict__ qw,
    const float* __restrict__ Wt, const float* __restrict__ W1,
    const float* __restrict__ W2, const float* __restrict__ at,
    int* __restrict__ cidx, int* __restrict__ ccnt,
    _Float16* __restrict__ WtT, float* __restrict__ ES,
    _Float16* __restrict__ ES16, float* __restrict__ Q,
    float* __restrict__ WSRC, float* __restrict__ WDST){
  __shared__ __align__(16) char smem[16896];
  int b = blockIdx.x;
  int tid = threadIdx.x;

  if (b < 128){
    // ---- colidx ----
    float (*tile)[33] = (float(*)[33])smem;
    int lt = b & 15, n = b >> 4;
    int l0 = lt*32;
    int l = tid & 31, eg = tid >> 5;
    for (int i = 0; i < 16; i++){
      int e = eg*16 + i;
      tile[e][l] = emap[((size_t)n*128 + e)*512 + l0 + l];
    }
    __syncthreads();
    if (tid < 32){
      int ll = tid;
      int bb = n*512 + l0 + ll;
      int* outp = cidx + (size_t)bb*128;
      int cnt = 0;
      for (int e = 0; e < 128; e++){
        if (tile[e][ll] != 0.f) outp[cnt++] = e;
      }
      ccnt[bb] = cnt;
    }
  } else if (b < 224){
    // ---- wtprep ----
    _Float16 (*tile)[65] = (_Float16(*)[65])smem;
    int rb = b - 128;
    int kt = rb & 7, ht = rb >> 3;
    for (int rep = 0; rep < 16; rep++){
      int linear = rep*256 + tid;
      int k = linear >> 6, f = linear & 63;
      tile[f][k] = (_Float16)Wt[((size_t)ht*512 + kt*64 + k)*64 + f];
    }
    __syncthreads();
    for (int rep = 0; rep < 16; rep++){
      int linear = rep*256 + tid;
      int f = linear >> 6, k = linear & 63;
      WtT[((size_t)ht*64 + f)*512 + kt*64 + k] = tile[f][k];
    }
  } else if (b < 1248){
    // ---- ent_state ----
    int* idx_l = (int*)smem;
    int* cnt_p = (int*)(smem + 2048);
    int ne = b - 224;
    int n = ne >> 7;
    if (tid < 64){
      int total = 0;
      for (int base = 0; base < 512; base += 64){
        float m = emap[(size_t)ne*512 + base + tid];
        unsigned long long mask = __ballot(m != 0.f);
        int pos = __popcll(mask & ((1ull << tid) - 1ull));
        if (m != 0.f) idx_l[total + pos] = base + tid;
        total += __popcll(mask);
      }
      if (tid == 0) *cnt_p = total;
    }
    __syncthreads();
    int cnt = *cnt_p;
    const float* dbase = doc + (size_t)n*512*256 + tid;
    const float* mrow = emap + (size_t)ne*512;
    float sum = 0.f, mx = -3.402823e38f, msum = 0.f;
    for (int i = 0; i < cnt; i++){
      int l = idx_l[i];
      float m = mrow[l];
      float v = m * dbase[(size_t)l*256];
      sum += v; mx = fmaxf(mx, v); msum += m;
    }
    if (cnt < 512) mx = fmaxf(mx, 0.f);
    float elen = (msum == 0.f) ? 1.f : msum;
    float mean = sum / elen;
    float* o = ES + (size_t)ne*512;
    o[tid] = mx;
    o[256 + tid] = mean;
    _Float16* o16 = ES16 + (size_t)ne*512;
    o16[tid] = (_Float16)mx;
    o16[256 + tid] = (_Float16)mean;
  } else if (b < 1312){
    // ---- query2 ----
    float (*part)[64] = (float(*)[64])smem;
    int rb = b - 1248;
    int n = rb >> 3, ct = rb & 7;
    int col = ct*64 + (tid & 63), ks = tid >> 6;
    const float* qvp = qv + n*512 + ks*128;
    const float* qwp = qw + (size_t)(ks*128)*512 + col;
    float acc = 0.f;
    for (int k = 0; k < 128; k++) acc += qvp[k] * qwp[(size_t)k*512];
    part[ks][tid & 63] = acc;
    __syncthreads();
    if (tid < 64)
      Q[n*512 + ct*64 + tid] = part[0][tid] + part[1][tid] + part[2][tid] + part[3][tid];
  } else {
    // ---- qattn ----
    float* qv_s = (float*)smem;
    float* partb = qv_s + 512;
    float* qg1 = partb + 256;
    int rb = b - 1312;
    int ht = rb >> 3, n = rb & 7;
    int f = tid & 127, kh = tid >> 7;
    for (int i = tid; i < 512; i += 256) qv_s[i] = qv[n*512 + i];
    __syncthreads();
    const float* w1 = W1 + (size_t)ht*512*128 + (size_t)kh*256*128 + f;
    float acc = 0.f;
    for (int k = 0; k < 256; k++) acc += qv_s[kh*256 + k] * w1[(size_t)k*128];
    partb[kh*128 + f] = acc;
    __syncthreads();
    if (kh == 0) qg1[f] = fmaxf(partb[f] + partb[128 + f], 0.f);
    __syncthreads();
    const float* w2 = W2 + (size_t)ht*128*128 + (size_t)kh*64*128 + f;
    float acc2 = 0.f;
    for (int g = 0; g < 64; g++) acc2 += qg1[kh*64 + g] * w2[(size_t)g*128];
    partb[kh*128 + f] = acc2;
    __syncthreads();
    if (kh == 0){
      float coef = sigm(partb[f] + partb[128 + f]) * at[ht*128 + f];
      if (f < 64) WSRC[(ht*8 + n)*64 + f] = coef;
      else        WDST[(ht*8 + n)*64 + f - 64] = coef;
    }
  }
}

// =============== MEGA-2: qscore2 (4 waves/block) + hall ===============
__global__ __launch_bounds__(256) void k_mega2(
    const float* __restrict__ ES, const float* __restrict__ Q,
    const float* __restrict__ emask, const _Float16* __restrict__ ES16,
    const _Float16* __restrict__ WtT, float* __restrict__ sm_out,
    float* __restrict__ AM, float* __restrict__ HALL){
  int b = blockIdx.x;
  int tid = threadIdx.x;
  if (b < 256){
    int wv = tid >> 6, lane = tid & 63;
    int ne = b*4 + wv;
    int n = ne >> 7;
    const float* es = ES + (size_t)ne*512;
    const float* q = Q + n*512;
    float a = 0.f;
    for (int k = lane; k < 512; k += 64) a += es[k] * q[k];
    #pragma unroll
    for (int o = 32; o > 0; o >>= 1) a += __shfl_xor(a, o, 64);
    if (lane == 0){
      float s = (a * (1.f/512.f)) * emask[ne];
      sm_out[ne] = s;
      AM[ne] = sigm(s);
    }
  } else {
    int idx = b - 256;
    int net = idx & 15, ht = idx >> 4;
    int lane = tid & 63, w = tid >> 6;
    int wm = w >> 1, wg = w & 1;
    int m0 = net*64 + wm*32;
    int f0 = wg*32;
    int lr = lane & 15, lk8 = (lane >> 4) * 8;

    const _Float16* a0p = ES16 + (size_t)(m0 + lr)*512 + lk8;
    const _Float16* a1p = a0p + (size_t)16*512;
    const _Float16* b0p = WtT + ((size_t)ht*64 + f0 + lr)*512 + lk8;
    const _Float16* b1p = b0p + (size_t)16*512;

    f32x4 acc[2][2] = {};
    for (int k0 = 0; k0 < 512; k0 += 32){
      f16x8 af[2], bfr[2];
      af[0] = *(const f16x8*)a0p;
      af[1] = *(const f16x8*)a1p;
      bfr[0] = *(const f16x8*)b0p;
      bfr[1] = *(const f16x8*)b1p;
      a0p += 32; a1p += 32; b0p += 32; b1p += 32;
      #pragma unroll
      for (int im = 0; im < 2; im++)
        #pragma unroll
        for (int ig = 0; ig < 2; ig++)
          acc[im][ig] = __builtin_amdgcn_mfma_f32_16x16x32_f16(af[im], bfr[ig], acc[im][ig], 0, 0, 0);
    }
    int crow = (lane >> 4) * 4;
    int ccol = lane & 15;
    #pragma unroll
    for (int im = 0; im < 2; im++)
      #pragma unroll
      for (int ig = 0; ig < 2; ig++){
        int f = f0 + ig*16 + ccol;
        #pragma unroll
        for (int r = 0; r < 4; r++){
          int m = m0 + im*16 + crow + r;
          HALL[((size_t)ht*1024 + m)*64 + f] = acc[im][ig][r];
        }
      }
  }
}

// ---------------- K7: fused srcdst + typed scores -> softmax -> heads ----------------
// src/dst projections computed in-block from WSRC/WDST x HALL (replaces the
// separate k_srcdst launch).
__global__ void k_attn(const float* __restrict__ HALL, const float* __restrict__ WSRC,
                       const float* __restrict__ WDST, const float* __restrict__ AM,
                       const int* __restrict__ adj, float* __restrict__ ES2,
                       float* __restrict__ out_ent){
  int b = blockIdx.x;                  // 256 = h(4) x n(8) x chunk(8)
  int h = b >> 6, n = (b >> 3) & 7, chunk = b & 7;
  int i0 = chunk*16;
  int tid = threadIdx.x;               // 128
  __shared__ float ws_l[3][64], wd_l[3][64];
  __shared__ float dst_l[3][128];
  __shared__ float src_l[3][16];
  __shared__ float hl[128][65];
  __shared__ float coef_l[128];
  __shared__ float redbuf[2];
  __shared__ float part2[2][64];
  for (int idx = tid; idx < 192; idx += 128){
    int t = idx >> 6, f = idx & 63;
    ws_l[t][f] = WSRC[((h*3 + t)*8 + n)*64 + f];
    wd_l[t][f] = WDST[((h*3 + t)*8 + n)*64 + f];
  }
  __syncthreads();
  // dst_l[t][j=tid] = dot64(HALL[h*3+t][n*128+j], wd_l[t])
  #pragma unroll
  for (int t = 0; t < 3; t++){
    const float* hrow = HALL + ((size_t)(h*3 + t)*1024 + n*128 + tid)*64;
    float d = 0.f;
    #pragma unroll 8
    for (int f = 0; f < 64; f++) d += hrow[f] * wd_l[t][f];
    dst_l[t][tid] = d;
  }
  if (tid < 48){
    int t = tid >> 4, r = tid & 15;
    const float* hrow = HALL + ((size_t)(h*3 + t)*1024 + n*128 + i0 + r)*64;
    float s = 0.f;
    #pragma unroll 8
    for (int f = 0; f < 64; f++) s += hrow[f] * ws_l[t][f];
    src_l[t][r] = s;
  }
  for (int idx = tid; idx < 8192; idx += 128){
    int j = idx >> 6, f = idx & 63;
    hl[j][f] = HALL[((size_t)(h*3 + 2)*1024 + n*128 + j)*64 + f] * AM[n*128 + j];
  }
  __syncthreads();
  const int* arow = adj + (size_t)n*128*128;
  int w = tid >> 6, f = tid & 63;
  for (int r = 0; r < 16; r++){
    int i = i0 + r;
    int a = arow[(size_t)i*128 + tid];
    float s;
    if (a > 0){
      float v = src_l[a-1][r] + dst_l[a-1][tid];
      s = v > 0.f ? v : 0.2f*v;
    } else s = -1e30f;
    float m = s;
    #pragma unroll
    for (int o = 32; o > 0; o >>= 1) m = fmaxf(m, __shfl_xor(m, o, 64));
    if ((tid & 63) == 0) redbuf[w] = m;
    __syncthreads();
    float mx = fmaxf(redbuf[0], redbuf[1]);
    float p = expf(s - mx);
    float ps = p;
    #pragma unroll
    for (int o = 32; o > 0; o >>= 1) ps += __shfl_xor(ps, o, 64);
    __syncthreads();
    if ((tid & 63) == 0) redbuf[w] = ps;
    __syncthreads();
    float denom = redbuf[0] + redbuf[1];
    coef_l[tid] = p / denom;
    __syncthreads();
    float acc = 0.f;
    for (int jj = 0; jj < 64; jj++) acc += coef_l[w*64 + jj] * hl[w*64 + jj][f];
    part2[w][f] = acc;
    __syncthreads();
    if (tid < 64){
      float v = fmaxf(part2[0][tid] + part2[1][tid], 0.f);
      size_t oidx = ((size_t)n*128 + i)*256 + h*64 + tid;
      ES2[oidx] = v;
      out_ent[oidx] = v;
    }
    __syncthreads();
  }
}

// ---------------- K8: expand entities back to tokens (entity half only) ----------------
// INP is now [4096][256] — just the entity expansion. The doc half is read
// directly by k_gatein from `doc` (identical row-linear layout).
__global__ void k_expand(const float* __restrict__ ES2, const float* __restrict__ emap,
                         const int* __restrict__ cidx, const int* __restrict__ ccnt,
                         float* __restrict__ INP){
  int b = blockIdx.x;       // n*512+l, 4096
  int n = b >> 9, l = b & 511;
  int tid = threadIdx.x;    // 256
  int cnt = ccnt[b];
  const int* idx = cidx + (size_t)b*128;
  float acc = 0.f;
  const float* e2 = ES2 + (size_t)n*128*256 + tid;
  for (int i = 0; i < cnt; i++){
    int e = idx[i];
    float m = emap[((size_t)n*128 + e)*512 + l];
    acc += m * e2[(size_t)e*256];
  }
  INP[(size_t)b*256 + tid] = acc;
}

// ---------------- K9: input-projection GEMMs via bf16 MFMA ----------------
// A operand: k<256 from INP (entity half), k>=256 directly from doc.
// Writes GATE-INTERLEAVED layout: G[m][j*4 + q], original g = q*128 + j.
__global__ __launch_bounds__(256) void k_gatein(const float* __restrict__ INP,
                         const float* __restrict__ doc,
                         const float* __restrict__ Wf, const float* __restrict__ Wb,
                         const float* __restrict__ bihf, const float* __restrict__ bhhf,
                         const float* __restrict__ bihb, const float* __restrict__ bhhb,
                         float* __restrict__ GF, float* __restrict__ GB){
  int mt = blockIdx.x, gt = blockIdx.y, dir = blockIdx.z;
  const float* W = dir ? Wb : Wf;
  float* Gout = dir ? GB : GF;
  const float* bi = dir ? bihb : bihf;
  const float* bh = dir ? bhhb : bhhf;
  int tid = threadIdx.x;
  int lane = tid & 63, w = tid >> 6;
  int wm = w >> 1, wg = w & 1;
  int m0 = mt*64 + wm*32;
  int g0 = gt*64 + wg*32;
  int lr = lane & 15, lk8 = (lane >> 4) * 8;

  const float* b0p = W + (size_t)(g0 + lr)*512 + lk8;
  const float* b1p = b0p + (size_t)16*512;

  f32x4 acc[2][2] = {};
  #pragma unroll
  for (int half = 0; half < 2; half++){
    const float* base = half ? doc : INP;
    const float* ap0 = base + (size_t)(m0 + lr)*256 + lk8;
    const float* ap1 = ap0 + (size_t)16*256;
    for (int k0 = 0; k0 < 256; k0 += 32){
      bf16x8 af[2], bfr[2];
      {
        float4 u = *(const float4*)ap0, v = *(const float4*)(ap0 + 4);
        bf16x8 r; r[0]=(short)f2bf(u.x); r[1]=(short)f2bf(u.y); r[2]=(short)f2bf(u.z); r[3]=(short)f2bf(u.w);
        r[4]=(short)f2bf(v.x); r[5]=(short)f2bf(v.y); r[6]=(short)f2bf(v.z); r[7]=(short)f2bf(v.w);
        af[0]=r;
      }
      {
        float4 u = *(const float4*)ap1, v = *(const float4*)(ap1 + 4);
        bf16x8 r; r[0]=(short)f2bf(u.x); r[1]=(short)f2bf(u.y); r[2]=(short)f2bf(u.z); r[3]=(short)f2bf(u.w);
        r[4]=(short)f2bf(v.x); r[5]=(short)f2bf(v.y); r[6]=(short)f2bf(v.z); r[7]=(short)f2bf(v.w);
        af[1]=r;
      }
      {
        float4 u = *(const float4*)b0p, v = *(const float4*)(b0p + 4);
        bf16x8 r; r[0]=(short)f2bf(u.x); r[1]=(short)f2bf(u.y); r[2]=(short)f2bf(u.z); r[3]=(short)f2bf(u.w);
        r[4]=(short)f2bf(v.x); r[5]=(short)f2bf(v.y); r[6]=(short)f2bf(v.z); r[7]=(short)f2bf(v.w);
        bfr[0]=r;
      }
      {
        float4 u = *(const float4*)b1p, v = *(const float4*)(b1p + 4);
        bf16x8 r; r[0]=(short)f2bf(u.x); r[1]=(short)f2bf(u.y); r[2]=(short)f2bf(u.z); r[3]=(short)f2bf(u.w);
        r[4]=(short)f2bf(v.x); r[5]=(short)f2bf(v.y); r[6]=(short)f2bf(v.z); r[7]=(short)f2bf(v.w);
        bfr[1]=r;
      }
      ap0 += 32; ap1 += 32; b0p += 32; b1p += 32;
      #pragma unroll
      for (int im = 0; im < 2; im++)
        #pragma unroll
        for (int ig = 0; ig < 2; ig++)
          acc[im][ig] = __builtin_amdgcn_mfma_f32_16x16x32_bf16(af[im], bfr[ig], acc[im][ig], 0, 0, 0);
    }
  }
  int crow = (lane >> 4) * 4;
  int ccol = lane & 15;
  #pragma unroll
  for (int im = 0; im < 2; im++)
    #pragma unroll
    for (int ig = 0; ig < 2; ig++){
      int g = g0 + ig*16 + ccol;
      float bias = bi[g] + bh[g];
      int p = (g & 127)*4 + (g >> 7);
      #pragma unroll
      for (int r = 0; r < 4; r++){
        int m = m0 + im*16 + crow + r;
        Gout[(size_t)m*512 + p] = acc[im][ig][r] + bias;
      }
    }
}

// ---------------- K10: LSTM recurrence (R7 version — measured best) ----------------
__global__ __launch_bounds__(256) void k_lstm(const float* __restrict__ GF,
                                              const float* __restrict__ GB,
                                              const float* __restrict__ Whhf,
                                              const float* __restrict__ Whhb,
                                              float* __restrict__ out){
  int b = blockIdx.x;          // 16
  int dir = b >> 3, n = b & 7;
  const float* G = dir ? GB : GF;
  const float* Whh = dir ? Whhb : Whhf;
  int tid = threadIdx.x;       // 256
  int j = tid >> 1;            // unit 0..127
  int s = tid & 1;             // k-slice half

  h2 wreg[4][32];
  #pragma unroll
  for (int q = 0; q < 4; q++){
    const float* wp = Whh + (size_t)(q*128 + j)*128 + 64*s;
    #pragma unroll
    for (int kk = 0; kk < 32; kk++){
      h2 p; p[0] = (_Float16)wp[2*kk]; p[1] = (_Float16)wp[2*kk+1];
      wreg[q][kk] = p;
    }
  }

  __shared__ __align__(16) _Float16 h_l[2][128];
  if (tid < 128) h_l[0][tid] = (_Float16)0.f;

  const float4* Gp = (const float4*)(G + (size_t)n*512*512) + (dir ? (size_t)511*128 : 0) + j;
  const int gstep = dir ? -128 : 128;
  float* outp = out + (size_t)n*512*256 + (dir ? (size_t)511*256 : 0) + dir*128 + j;
  const int ostep = dir ? -256 : 256;

  float4 ga, gb, gc, gd;
  ga = *Gp; Gp += gstep;
  gb = *Gp; Gp += gstep;
  gc = *Gp; Gp += gstep;
  gd = *Gp; Gp += gstep;
  float c = 0.f;
  __syncthreads();

#define LSTM_STEP(RB, GREG)                                                    \
  {                                                                            \
    const uint4* hb = (const uint4*)(&h_l[RB][64*s]);                          \
    uint4 hv[8];                                                               \
    _Pragma("unroll")                                                          \
    for (int r = 0; r < 8; r++) hv[r] = hb[r];                                 \
    float gci = GREG.x, gcf = GREG.y, gcg = GREG.z, gco = GREG.w;              \
    GREG = *Gp; Gp += gstep;                                                   \
    float accf[4];                                                             \
    _Pragma("unroll")                                                          \
    for (int q = 0; q < 4; q++){                                               \
      h2 a0; a0[0]=(_Float16)0.f; a0[1]=(_Float16)0.f; h2 a1 = a0;             \
      _Pragma("unroll")                                                        \
      for (int r = 0; r < 8; r++){                                             \
        a0 += wreg[q][4*r+0] * u2h(hv[r].x);                                   \
        a1 += wreg[q][4*r+1] * u2h(hv[r].y);                                   \
        a0 += wreg[q][4*r+2] * u2h(hv[r].z);                                   \
        a1 += wreg[q][4*r+3] * u2h(hv[r].w);                                   \
      }                                                                        \
      h2 hs = a0 + a1;                                                         \
      accf[q] = (float)hs[0] + (float)hs[1];                                   \
    }                                                                          \
    _Pragma("unroll")                                                          \
    for (int q = 0; q < 4; q++){                                               \
      accf[q] += qperm<0xB1>(accf[q]);                                         \
    }                                                                          \
    float vi = accf[0] + gci, vf = accf[1] + gcf;                              \
    float vg = accf[2] + gcg, vo = accf[3] + gco;                              \
    c = fsigm(vf) * c + fsigm(vi) * ftanh(vg);                                 \
    float hval = fsigm(vo) * ftanh(c);                                         \
    if (s == 0) h_l[RB^1][j] = (_Float16)hval;                                 \
    else        *outp = hval;                                                  \
    outp += ostep;                                                             \
    asm volatile("s_waitcnt lgkmcnt(0)\n\ts_barrier" ::: "memory");            \
  }

  for (int t = 0; t < 512; t += 4){
    LSTM_STEP(0, ga)
    LSTM_STEP(1, gb)
    LSTM_STEP(0, gc)
    LSTM_STEP(1, gd)
  }
#undef LSTM_STEP
}

extern "C" void kernel_launch(void* const* d_in, const int* in_sizes, int n_in,
                              void* d_out, int out_size, void* d_ws, size_t ws_size,
                              hipStream_t stream){
  const float* doc   = (const float*)d_in[0];
  const float* qvec  = (const float*)d_in[1];
  const float* emap  = (const float*)d_in[3];
  const float* emask = (const float*)d_in[4];
  const float* qw    = (const float*)d_in[5];
  const float* Wt    = (const float*)d_in[6];
  const float* at    = (const float*)d_in[7];
  const float* qa1   = (const float*)d_in[8];
  const float* qa2   = (const float*)d_in[9];
  const float* Wihf  = (const float*)d_in[10];
  const float* Whhf  = (const float*)d_in[11];
  const float* bihf  = (const float*)d_in[12];
  const float* bhhf  = (const float*)d_in[13];
  const float* Wihb  = (const float*)d_in[14];
  const float* Whhb  = (const float*)d_in[15];
  const float* bihb  = (const float*)d_in[16];
  const float* bhhb  = (const float*)d_in[17];
  const int*   adj   = (const int*)d_in[19];

  float* out = (float*)d_out;
  float* out_doc = out;                         // 8*512*256
  float* out_ent = out + 8*512*256;             // 8*128*256
  float* out_sm  = out_ent + 8*128*256;         // 8*128

  float* w = (float*)d_ws;
  float* ES   = w; w += 8*128*512;
  float* AM   = w; w += 8*128;
  float* Q    = w; w += 8*512;
  float* HALL = w; w += 12*1024*64;
  float* WSRC = w; w += 12*8*64;
  float* WDST = w; w += 12*8*64;
  float* ES2  = w; w += 8*128*256;
  float* INP  = w; w += 8*512*256;              // entity half only
  float* GF   = w; w += 8*512*512;
  w += 4096;                                    // prefetch overrun pad
  float* GB   = w; w += 8*512*512;
  w += 4096;                                    // safety pad
  _Float16* ES16 = (_Float16*)w; w += 8*128*512/2;
  _Float16* WtT  = (_Float16*)w; w += 12*64*512/2;
  int* cidx = (int*)w; w += 4096*128;
  int* ccnt = (int*)w; w += 4096;

  hipLaunchKernelGGL(k_mega1,  dim3(1408), dim3(256), 0, stream,
                     doc, emap, qvec, qw, Wt, qa1, qa2, at,
                     cidx, ccnt, WtT, ES, ES16, Q, WSRC, WDST);
  hipLaunchKernelGGL(k_mega2,  dim3(448),  dim3(256), 0, stream,
                     ES, Q, emask, ES16, WtT, out_sm, AM, HALL);
  hipLaunchKernelGGL(k_attn,   dim3(256),  dim3(128), 0, stream, HALL, WSRC, WDST, AM, adj, ES2, out_ent);
  hipLaunchKernelGGL(k_expand, dim3(4096), dim3(256), 0, stream, ES2, emap, cidx, ccnt, INP);
  hipLaunchKernelGGL(k_gatein, dim3(64,8,2), dim3(256), 0, stream, INP, doc, Wihf, Wihb, bihf, bhhf, bihb, bhhb, GF, GB);
  hipLaunchKernelGGL(k_lstm,   dim3(16),   dim3(256), 0, stream, GF, GB, Whhf, Whhb, out_doc);
}